// Round 5
// baseline (210.938 us; speedup 1.0000x reference)
//
#include <hip/hip_runtime.h>
#include <hip/hip_bf16.h>
#include <cstdint>
#include <cstddef>

// out[b,c] = bias[c] + sum_i x[b,i]*(W1[i,c] + sum_j W2[i,j,c]*x[b,j])
// W flat layout: W1[i,c] = W[i*10+c]; W2[i,j,c] = W[7840 + i*7840 + j*10 + c]
//
// Single-dispatch structure: memset(out) + one kernel; cross-block i/j-chunk
// partials are combined with device-scope f32 atomicAdd (686 adds per output,
// jitter ~1e-5 << 0.5125 threshold). Block 0 folds in bias (covers each (b,c)
// exactly once across its 8 waves).

typedef short short8 __attribute__((ext_vector_type(8)));
typedef float f32x4 __attribute__((ext_vector_type(4)));

#define NB   128
#define DD   784
#define NC   10
#define KCH  56     // j-chunk per block (14*56 = 784)
#define NKC  14
#define IG   16     // i per block
#define NG   49
#define NBLK (NG*NKC)   // 686
#define LDK  72         // LDS row stride in bf16 (64 + 8 pad; 144B = odd multiple of 16B)
#define LDKU 36         // same in u32

__device__ __forceinline__ uint32_t f2bfbits(float f) {
  // round-to-nearest-even f32 -> bf16 (finite inputs)
  uint32_t u = __builtin_bit_cast(uint32_t, f);
  u += 0x7FFFu + ((u >> 16) & 1u);
  return u >> 16;
}

__global__ __launch_bounds__(512, 4)
void bilinear_main(const float* __restrict__ x, const float* __restrict__ W,
                   const float* __restrict__ bias, float* __restrict__ out) {
  __shared__ unsigned short ldsW[160 * LDK];  // 23,040 B
  uint32_t* lds32 = (uint32_t*)ldsW;

  const int tid  = threadIdx.x;
  const int blk  = blockIdx.x;
  const int g    = blk / NKC;
  const int kc   = blk - g * NKC;
  const int i0   = g * IG;
  const int lane = tid & 63;
  const int w    = tid >> 6;      // wave 0..7
  const int wm   = w >> 2;        // c half (tiles 5*wm .. 5*wm+4)
  const int bq2  = w & 3;         // batch quarter (32 batches)
  const int l15  = lane & 15;
  const int q    = lane >> 4;     // lane quad
  const int jbase = kc * KCH;

  // ---- stage W2 chunk -> LDS bf16 transposed; coalesced float4 loads ----
  // group tid = il*28 + k covers i=i0+il, j = jbase+2k..2k+1, c=0..9
  // (20 contiguous, 16B-aligned floats). One round: tid < 448.
  if (tid < 448) {
    const int il = tid / 28;
    const int k  = tid - il * 28;
    const float* p = W + 7840 + (size_t)(i0 + il) * 7840 + (size_t)jbase * NC + k * 20;
    const float4 a0 = ((const float4*)p)[0];
    const float4 a1 = ((const float4*)p)[1];
    const float4 a2 = ((const float4*)p)[2];
    const float4 a3 = ((const float4*)p)[3];
    const float4 a4 = ((const float4*)p)[4];
    const float v[20] = {a0.x,a0.y,a0.z,a0.w, a1.x,a1.y,a1.z,a1.w,
                         a2.x,a2.y,a2.z,a2.w, a3.x,a3.y,a3.z,a3.w,
                         a4.x,a4.y,a4.z,a4.w};
    #pragma unroll
    for (int c = 0; c < 10; ++c) {
      const uint32_t lo = f2bfbits(v[c]);
      const uint32_t hi = f2bfbits(v[c + 10]);
      lds32[(c * 16 + il) * LDKU + k] = lo | (hi << 16);
    }
  }

  // ---- zero the k-pad columns j in [56,64) for all 160 rows ----
  #pragma unroll
  for (int z = 0; z < 2; ++z) {
    const int idx = z * 512 + tid;          // 0..639 used
    if (idx < 160 * 4) {
      const int row  = idx >> 2;
      const int colu = idx & 3;
      lds32[row * LDKU + 28 + colu] = 0;
    }
  }

  // ---- B operand: x-hat fragments (lane: b = bq2*32+bg*16+l15, j = jbase+ks*32+q*8+e) ----
  short8 bq[2][2];
  #pragma unroll
  for (int bg = 0; bg < 2; ++bg) {
    const int b = bq2 * 32 + bg * 16 + l15;
    const float* xrow = x + (size_t)b * DD + jbase;
    #pragma unroll
    for (int ks = 0; ks < 2; ++ks) {
      const int jloc = ks * 32 + q * 8;
      float v[8];
      if (jloc < KCH) {
        const float4 p0 = *(const float4*)(xrow + jloc);
        const float4 p1 = *(const float4*)(xrow + jloc + 4);
        v[0] = p0.x; v[1] = p0.y; v[2] = p0.z; v[3] = p0.w;
        v[4] = p1.x; v[5] = p1.y; v[6] = p1.z; v[7] = p1.w;
      } else {
        #pragma unroll
        for (int e = 0; e < 8; ++e) v[e] = 0.f;
      }
      short8 s;
      #pragma unroll
      for (int e = 0; e < 8; ++e) s[e] = (short)f2bfbits(v[e]);
      bq[bg][ks] = s;
    }
  }

  // ---- hoisted epilogue weights: x[b, i] f32 (i = i0 + q*4 + r) ----
  float xv[2][4];
  #pragma unroll
  for (int bg = 0; bg < 2; ++bg) {
    const int b = bq2 * 32 + bg * 16 + l15;
    #pragma unroll
    for (int r = 0; r < 4; ++r)
      xv[bg][r] = x[(size_t)b * DD + i0 + q * 4 + r];
  }

  __syncthreads();

  // ---- MFMA: A = W2-tile (rows: c fixed per tile, m = i-local), B = x-hat ----
  float yacc[2][5] = {};   // [bg][t]  (c = wm*5 + t static per slot)
  const int tbase = wm * 5;
  #pragma unroll
  for (int t = 0; t < 5; ++t) {
    const int tile = tbase + t;          // tile index == c
    f32x4 acc[2] = {};
    const unsigned short* arow = &ldsW[(tile * 16 + l15) * LDK + q * 8];
    #pragma unroll
    for (int ks = 0; ks < 2; ++ks) {
      const short8 a = *(const short8*)(arow + ks * 32);
      #pragma unroll
      for (int bg = 0; bg < 2; ++bg)
        acc[bg] = __builtin_amdgcn_mfma_f32_16x16x32_bf16(a, bq[bg][ks], acc[bg], 0, 0, 0);
    }
    // epilogue: y[b,c] += x[b,i] * (T[b,i,c] + W1[i,c] once at kc==0)
    #pragma unroll
    for (int r = 0; r < 4; ++r) {
      float w1 = 0.f;
      if (kc == 0) w1 = W[(i0 + q * 4 + r) * NC + tile];
      #pragma unroll
      for (int bg = 0; bg < 2; ++bg)
        yacc[bg][t] += xv[bg][r] * (acc[bg][r] + w1);
    }
  }

  // ---- reduce over lane-quads (each q holds a different i-subset), emit atomics ----
  #pragma unroll
  for (int bg = 0; bg < 2; ++bg) {
    #pragma unroll
    for (int t = 0; t < 5; ++t) {
      float v = yacc[bg][t];
      v += __shfl_down(v, 16);
      v += __shfl_down(v, 32);
      if (q == 0) {
        const int bc = (bq2 * 32 + bg * 16 + l15) * NC + tbase + t;
        if (blk == 0) v += bias[tbase + t];
        atomicAdd(&out[bc], v);
      }
    }
  }
}

extern "C" void kernel_launch(void* const* d_in, const int* in_sizes, int n_in,
                              void* d_out, int out_size, void* d_ws, size_t ws_size,
                              hipStream_t stream) {
  const float* x    = (const float*)d_in[0];
  const float* W    = (const float*)d_in[1];
  const float* bias = (const float*)d_in[2];
  float* out = (float*)d_out;
  (void)d_ws; (void)ws_size;

  hipMemsetAsync(d_out, 0, (size_t)NB * NC * sizeof(float), stream);
  bilinear_main<<<NBLK, 512, 0, stream>>>(x, W, bias, out);
}

// Round 6
// 23.943 us; speedup vs baseline: 8.8098x; 8.8098x over previous
//
#include <hip/hip_runtime.h>
#include <hip/hip_bf16.h>
#include <cstdint>
#include <cstddef>

// out[b,c] = bias[c] + sum_i x[b,i]*(W1[i,c] + sum_j W2[i,j,c]*x[b,j])
// W flat layout: W1[i,c] = W[i*10+c]; W2[i,j,c] = W[7840 + i*7840 + j*10 + c]
//
// Two deterministic dispatches:
//   bilinear_main: grid 686 = 49 i-groups x 14 j-chunks; per-block partial
//     out-contributions written CONTIGUOUSLY to P[blk][b*10+c] (5 KB/block).
//   reduce_partials: 40 blocks x 320 thr, coalesced column-sum over 686 rows,
//     adds bias, writes out directly. No atomics anywhere (round-5 lesson:
//     686-way same-address atomic contention cost ~190 us).

typedef short short8 __attribute__((ext_vector_type(8)));
typedef float f32x4 __attribute__((ext_vector_type(4)));

#define NB   128
#define DD   784
#define NC   10
#define KCH  56     // j-chunk per block (14*56 = 784)
#define NKC  14
#define IG   16     // i per block
#define NG   49
#define NBLK (NG*NKC)   // 686
#define LDK  72         // LDS row stride in bf16 (64 + 8 pad; 144B = odd multiple of 16B)
#define LDKU 36         // same in u32
#define NOUT (NB*NC)    // 1280

__device__ __forceinline__ uint32_t f2bfbits(float f) {
  // round-to-nearest-even f32 -> bf16 (finite inputs)
  uint32_t u = __builtin_bit_cast(uint32_t, f);
  u += 0x7FFFu + ((u >> 16) & 1u);
  return u >> 16;
}

template <int ATOMIC>
__global__ __launch_bounds__(512, 4)
void bilinear_main(const float* __restrict__ x, const float* __restrict__ W,
                   const float* __restrict__ bias, float* __restrict__ P,
                   float* __restrict__ out) {
  __shared__ unsigned short ldsW[160 * LDK];  // 23,040 B
  uint32_t* lds32 = (uint32_t*)ldsW;

  const int tid  = threadIdx.x;
  const int blk  = blockIdx.x;
  const int g    = blk / NKC;
  const int kc   = blk - g * NKC;
  const int i0   = g * IG;
  const int lane = tid & 63;
  const int w    = tid >> 6;      // wave 0..7
  const int wm   = w >> 2;        // c half (tiles 5*wm .. 5*wm+4)
  const int bq2  = w & 3;         // batch quarter (32 batches)
  const int l15  = lane & 15;
  const int q    = lane >> 4;     // lane quad
  const int jbase = kc * KCH;

  // ---- zero the k-pad columns j in [56,64) for all 160 rows ----
  #pragma unroll
  for (int z = 0; z < 2; ++z) {
    const int idx = z * 512 + tid;          // 0..639 used
    if (idx < 160 * 4) {
      const int row  = idx >> 2;
      const int colu = idx & 3;
      lds32[row * LDKU + 28 + colu] = 0;
    }
  }

  // ---- stage W2 chunk -> LDS bf16 transposed; coalesced float4 loads ----
  // tid = il*28 + k covers i=i0+il, j = jbase+2k..2k+1, c=0..9
  // (20 contiguous, 16B-aligned floats). One round: tid < 448.
  if (tid < 448) {
    const int il = tid / 28;
    const int k  = tid - il * 28;
    const float* p = W + 7840 + (size_t)(i0 + il) * 7840 + (size_t)jbase * NC + k * 20;
    const float4 a0 = ((const float4*)p)[0];
    const float4 a1 = ((const float4*)p)[1];
    const float4 a2 = ((const float4*)p)[2];
    const float4 a3 = ((const float4*)p)[3];
    const float4 a4 = ((const float4*)p)[4];
    const float v[20] = {a0.x,a0.y,a0.z,a0.w, a1.x,a1.y,a1.z,a1.w,
                         a2.x,a2.y,a2.z,a2.w, a3.x,a3.y,a3.z,a3.w,
                         a4.x,a4.y,a4.z,a4.w};
    #pragma unroll
    for (int c = 0; c < 10; ++c) {
      const uint32_t lo = f2bfbits(v[c]);
      const uint32_t hi = f2bfbits(v[c + 10]);
      lds32[(c * 16 + il) * LDKU + k] = lo | (hi << 16);
    }
  }

  // ---- B operand: x-hat fragments (lane: b = bq2*32+bg*16+l15, j = jbase+ks*32+q*8+e) ----
  short8 bq[2][2];
  #pragma unroll
  for (int bg = 0; bg < 2; ++bg) {
    const int b = bq2 * 32 + bg * 16 + l15;
    const float* xrow = x + (size_t)b * DD + jbase;
    #pragma unroll
    for (int ks = 0; ks < 2; ++ks) {
      const int jloc = ks * 32 + q * 8;
      float v[8];
      if (jloc < KCH) {
        const float4 p0 = *(const float4*)(xrow + jloc);
        const float4 p1 = *(const float4*)(xrow + jloc + 4);
        v[0] = p0.x; v[1] = p0.y; v[2] = p0.z; v[3] = p0.w;
        v[4] = p1.x; v[5] = p1.y; v[6] = p1.z; v[7] = p1.w;
      } else {
        #pragma unroll
        for (int e = 0; e < 8; ++e) v[e] = 0.f;
      }
      short8 s;
      #pragma unroll
      for (int e = 0; e < 8; ++e) s[e] = (short)f2bfbits(v[e]);
      bq[bg][ks] = s;
    }
  }

  // ---- hoisted epilogue weights: one float4 per bg (i = i0 + q*4 .. +3) ----
  float xv[2][4];
  #pragma unroll
  for (int bg = 0; bg < 2; ++bg) {
    const int b = bq2 * 32 + bg * 16 + l15;
    const float4 xq = *(const float4*)(x + (size_t)b * DD + i0 + q * 4);
    xv[bg][0] = xq.x; xv[bg][1] = xq.y; xv[bg][2] = xq.z; xv[bg][3] = xq.w;
  }

  __syncthreads();

  // ---- MFMA: A = W2-tile (rows: c fixed per tile, m = i-local), B = x-hat ----
  float yacc[2][5] = {};   // [bg][t]  (c = wm*5 + t static per slot)
  const int tbase = wm * 5;
  #pragma unroll
  for (int t = 0; t < 5; ++t) {
    const int tile = tbase + t;          // tile index == c
    f32x4 acc[2] = {};
    const unsigned short* arow = &ldsW[(tile * 16 + l15) * LDK + q * 8];
    #pragma unroll
    for (int ks = 0; ks < 2; ++ks) {
      const short8 a = *(const short8*)(arow + ks * 32);
      #pragma unroll
      for (int bg = 0; bg < 2; ++bg)
        acc[bg] = __builtin_amdgcn_mfma_f32_16x16x32_bf16(a, bq[bg][ks], acc[bg], 0, 0, 0);
    }
    // epilogue: y[b,c] += x[b,i] * (T[b,i,c] + W1[i,c] once at kc==0)
    #pragma unroll
    for (int r = 0; r < 4; ++r) {
      float w1 = 0.f;
      if (kc == 0) w1 = W[(i0 + q * 4 + r) * NC + tile];
      #pragma unroll
      for (int bg = 0; bg < 2; ++bg)
        yacc[bg][t] += xv[bg][r] * (acc[bg][r] + w1);
    }
  }

  // ---- quad-reduce (each q holds a different i-subset), emit CONTIGUOUS ----
  #pragma unroll
  for (int bg = 0; bg < 2; ++bg) {
    #pragma unroll
    for (int t = 0; t < 5; ++t) {
      float v = yacc[bg][t];
      v += __shfl_down(v, 16);
      v += __shfl_down(v, 32);
      if (q == 0) {
        const int b = bq2 * 32 + bg * 16 + l15;
        if constexpr (ATOMIC == 0) {
          // P[blk][b*10 + c]: block writes 1280 consecutive floats (5 KB)
          P[(size_t)blk * NOUT + b * NC + tbase + t] = v;
        } else {
          float vv = v;
          if (blk == 0) vv += bias[tbase + t];
          atomicAdd(&out[b * NC + tbase + t], vv);
        }
      }
    }
  }
}

#define RRG 10   // row-groups per reduce block
#define BCB 32   // bc per reduce block

__global__ __launch_bounds__(320)
void reduce_partials(const float* __restrict__ P, const float* __restrict__ bias,
                     float* __restrict__ out) {
  __shared__ float red[RRG][BCB];
  const int tid = threadIdx.x;           // 0..319
  const int rg  = tid / BCB;             // 0..9
  const int bcl = tid - rg * BCB;        // 0..31
  const int bc  = blockIdx.x * BCB + bcl;  // 0..1279 (grid 40)

  float s = 0.f;
  #pragma unroll 4
  for (int r = rg; r < NBLK; r += RRG)
    s += P[(size_t)r * NOUT + bc];

  red[rg][bcl] = s;
  __syncthreads();
  if (rg == 0) {
    float t = s;
    #pragma unroll
    for (int k = 1; k < RRG; ++k) t += red[k][bcl];
    out[bc] = t + bias[bc % NC];
  }
}

extern "C" void kernel_launch(void* const* d_in, const int* in_sizes, int n_in,
                              void* d_out, int out_size, void* d_ws, size_t ws_size,
                              hipStream_t stream) {
  const float* x    = (const float*)d_in[0];
  const float* W    = (const float*)d_in[1];
  const float* bias = (const float*)d_in[2];
  float* out = (float*)d_out;
  float* P   = (float*)d_ws;

  const size_t need = (size_t)NBLK * NOUT * sizeof(float);  // ~3.5 MB
  if (ws_size >= need) {
    bilinear_main<0><<<NBLK, 512, 0, stream>>>(x, W, bias, P, out);
    reduce_partials<<<40, 320, 0, stream>>>(P, bias, out);
  } else {
    hipMemsetAsync(d_out, 0, (size_t)NOUT * sizeof(float), stream);
    bilinear_main<1><<<NBLK, 512, 0, stream>>>(x, W, bias, P, out);
  }
}

// Round 7
// 22.337 us; speedup vs baseline: 9.4436x; 1.0719x over previous
//
#include <hip/hip_runtime.h>
#include <hip/hip_bf16.h>
#include <cstdint>
#include <cstddef>

// out[b,c] = bias[c] + sum_i x[b,i]*(W1[i,c] + sum_j W2[i,j,c]*x[b,j])
// W flat layout: W1[i,c] = W[i*10+c]; W2[i,j,c] = W[7840 + i*7840 + j*10 + c]
//
// Two deterministic dispatches:
//   bilinear_main: grid 343 = 49 i-groups x 7 j-chunks (112 j each); per-block
//     partials written CONTIGUOUSLY to P[blk][b*10+c] (5 KB/block, 1.76 MB).
//   reduce_tree: 320 blocks (one per float4-column of out) x 512 threads;
//     thread t<343 does exactly ONE float4 load P4[t][f] -> all of P in flight
//     at once (latency-parallel), shfl tree + LDS combine, bias, store.
// No atomics anywhere (round-5 lesson: same-address atomic contention ~190us).

typedef short short8 __attribute__((ext_vector_type(8)));
typedef float f32x4 __attribute__((ext_vector_type(4)));

#define NB   128
#define DD   784
#define NC   10
#define KCH  112    // j-chunk per block (7*112 = 784)
#define NKC  7
#define IG   16     // i per block
#define NG   49
#define NBLK (NG*NKC)   // 343
#define LDK  136        // LDS row stride in bf16 (128 + 8 pad)
#define LDKU 68         // same in u32
#define NOUT (NB*NC)    // 1280

__device__ __forceinline__ uint32_t f2bfbits(float f) {
  // round-to-nearest-even f32 -> bf16 (finite inputs)
  uint32_t u = __builtin_bit_cast(uint32_t, f);
  u += 0x7FFFu + ((u >> 16) & 1u);
  return u >> 16;
}

template <int ATOMIC>
__global__ __launch_bounds__(512, 4)
void bilinear_main(const float* __restrict__ x, const float* __restrict__ W,
                   const float* __restrict__ bias, float* __restrict__ P,
                   float* __restrict__ out) {
  __shared__ unsigned short ldsW[160 * LDK];  // 43,520 B
  uint32_t* lds32 = (uint32_t*)ldsW;

  const int tid  = threadIdx.x;
  const int blk  = blockIdx.x;
  const int g    = blk / NKC;
  const int kc   = blk - g * NKC;
  const int i0   = g * IG;
  const int lane = tid & 63;
  const int w    = tid >> 6;      // wave 0..7
  const int wm   = w >> 2;        // c half (tiles 5*wm .. 5*wm+4)
  const int bq2  = w & 3;         // batch quarter (32 batches)
  const int l15  = lane & 15;
  const int q    = lane >> 4;     // lane quad
  const int jbase = kc * KCH;

  // ---- stage W2 chunk -> LDS bf16 transposed; coalesced float4 loads ----
  // group gi = il*56 + k covers i=i0+il, j = jbase+2k..2k+1, c=0..9
  // (20 contiguous, 16B-aligned floats).
  {
    const float* w2base = W + 7840 + (size_t)i0 * 7840 + (size_t)jbase * NC;
    #pragma unroll
    for (int half = 0; half < 2; ++half) {
      const int gi = half * 512 + tid;     // 0..895 used
      if (gi < 896) {
        const int il = gi / 56;
        const int k  = gi - il * 56;
        const float* p = w2base + il * 7840 + k * 20;
        const float4 a0 = ((const float4*)p)[0];
        const float4 a1 = ((const float4*)p)[1];
        const float4 a2 = ((const float4*)p)[2];
        const float4 a3 = ((const float4*)p)[3];
        const float4 a4 = ((const float4*)p)[4];
        const float v[20] = {a0.x,a0.y,a0.z,a0.w, a1.x,a1.y,a1.z,a1.w,
                             a2.x,a2.y,a2.z,a2.w, a3.x,a3.y,a3.z,a3.w,
                             a4.x,a4.y,a4.z,a4.w};
        #pragma unroll
        for (int c = 0; c < 10; ++c) {
          const uint32_t lo = f2bfbits(v[c]);
          const uint32_t hi = f2bfbits(v[c + 10]);
          lds32[(c * 16 + il) * LDKU + k] = lo | (hi << 16);
        }
      }
    }
    // zero the k-pad columns j in [112,128) for all 160 rows
    for (int idx = tid; idx < 160 * 8; idx += 512) {
      const int row  = idx >> 3;
      const int colu = idx & 7;
      lds32[row * LDKU + 56 + colu] = 0;
    }
  }

  // ---- B operand: x-hat fragments (lane: b = bq2*32+bg*16+l15, j = jbase+ks*32+q*8+e) ----
  short8 bq[2][4];
  #pragma unroll
  for (int bg = 0; bg < 2; ++bg) {
    const int b = bq2 * 32 + bg * 16 + l15;
    const float* xrow = x + (size_t)b * DD + jbase;
    #pragma unroll
    for (int ks = 0; ks < 4; ++ks) {
      const int jloc = ks * 32 + q * 8;
      float v[8];
      if (jloc < KCH) {
        const float4 p0 = *(const float4*)(xrow + jloc);
        const float4 p1 = *(const float4*)(xrow + jloc + 4);
        v[0] = p0.x; v[1] = p0.y; v[2] = p0.z; v[3] = p0.w;
        v[4] = p1.x; v[5] = p1.y; v[6] = p1.z; v[7] = p1.w;
      } else {
        #pragma unroll
        for (int e = 0; e < 8; ++e) v[e] = 0.f;
      }
      short8 s;
      #pragma unroll
      for (int e = 0; e < 8; ++e) s[e] = (short)f2bfbits(v[e]);
      bq[bg][ks] = s;
    }
  }

  // ---- hoisted epilogue weights: one float4 per bg (i = i0 + q*4 .. +3) ----
  float xv[2][4];
  #pragma unroll
  for (int bg = 0; bg < 2; ++bg) {
    const int b = bq2 * 32 + bg * 16 + l15;
    const float4 xq = *(const float4*)(x + (size_t)b * DD + i0 + q * 4);
    xv[bg][0] = xq.x; xv[bg][1] = xq.y; xv[bg][2] = xq.z; xv[bg][3] = xq.w;
  }

  __syncthreads();

  // ---- MFMA: A = W2-tile (rows: c fixed per tile, m = i-local), B = x-hat ----
  float yacc[2][5] = {};   // [bg][t]  (c = wm*5 + t static per slot)
  const int tbase = wm * 5;
  #pragma unroll
  for (int t = 0; t < 5; ++t) {
    const int tile = tbase + t;          // tile index == c
    f32x4 acc[2] = {};
    const unsigned short* arow = &ldsW[(tile * 16 + l15) * LDK + q * 8];
    #pragma unroll
    for (int ks = 0; ks < 4; ++ks) {
      const short8 a = *(const short8*)(arow + ks * 32);
      #pragma unroll
      for (int bg = 0; bg < 2; ++bg)
        acc[bg] = __builtin_amdgcn_mfma_f32_16x16x32_bf16(a, bq[bg][ks], acc[bg], 0, 0, 0);
    }
    // epilogue: y[b,c] += x[b,i] * (T[b,i,c] + W1[i,c] once at kc==0)
    #pragma unroll
    for (int r = 0; r < 4; ++r) {
      float w1 = 0.f;
      if (kc == 0) w1 = W[(i0 + q * 4 + r) * NC + tile];
      #pragma unroll
      for (int bg = 0; bg < 2; ++bg)
        yacc[bg][t] += xv[bg][r] * (acc[bg][r] + w1);
    }
  }

  // ---- quad-reduce (each q holds a different i-subset), emit CONTIGUOUS ----
  #pragma unroll
  for (int bg = 0; bg < 2; ++bg) {
    #pragma unroll
    for (int t = 0; t < 5; ++t) {
      float v = yacc[bg][t];
      v += __shfl_down(v, 16);
      v += __shfl_down(v, 32);
      if (q == 0) {
        const int b = bq2 * 32 + bg * 16 + l15;
        if constexpr (ATOMIC == 0) {
          P[(size_t)blk * NOUT + b * NC + tbase + t] = v;
        } else {
          float vv = v;
          if (blk == 0) vv += bias[tbase + t];
          atomicAdd(&out[b * NC + tbase + t], vv);
        }
      }
    }
  }
}

// One block per float4-column f of out (grid 320). Thread t<343 loads exactly
// one float4 P4[t][f]; shfl tree within waves, LDS combine across 8 waves.
__global__ __launch_bounds__(512)
void reduce_tree(const float* __restrict__ P, const float* __restrict__ bias,
                 float* __restrict__ out) {
  __shared__ float red[8][4];
  const int f = blockIdx.x;        // 0..319
  const int t = threadIdx.x;       // 0..511
  const int w = t >> 6, l = t & 63;

  float4 v = make_float4(0.f, 0.f, 0.f, 0.f);
  if (t < NBLK) v = ((const float4*)P)[(size_t)t * (NOUT / 4) + f];

  #pragma unroll
  for (int off = 32; off; off >>= 1) {
    v.x += __shfl_down(v.x, off);
    v.y += __shfl_down(v.y, off);
    v.z += __shfl_down(v.z, off);
    v.w += __shfl_down(v.w, off);
  }
  if (l == 0) { red[w][0] = v.x; red[w][1] = v.y; red[w][2] = v.z; red[w][3] = v.w; }
  __syncthreads();
  if (t == 0) {
    float4 s = make_float4(0.f, 0.f, 0.f, 0.f);
    #pragma unroll
    for (int k = 0; k < 8; ++k) {
      s.x += red[k][0]; s.y += red[k][1]; s.z += red[k][2]; s.w += red[k][3];
    }
    const int bc = f * 4;
    s.x += bias[bc % NC];
    s.y += bias[(bc + 1) % NC];
    s.z += bias[(bc + 2) % NC];
    s.w += bias[(bc + 3) % NC];
    *(float4*)&out[bc] = s;
  }
}

extern "C" void kernel_launch(void* const* d_in, const int* in_sizes, int n_in,
                              void* d_out, int out_size, void* d_ws, size_t ws_size,
                              hipStream_t stream) {
  const float* x    = (const float*)d_in[0];
  const float* W    = (const float*)d_in[1];
  const float* bias = (const float*)d_in[2];
  float* out = (float*)d_out;
  float* P   = (float*)d_ws;

  const size_t need = (size_t)NBLK * NOUT * sizeof(float);  // ~1.76 MB
  if (ws_size >= need) {
    bilinear_main<0><<<NBLK, 512, 0, stream>>>(x, W, bias, P, out);
    reduce_tree<<<NOUT / 4, 512, 0, stream>>>(P, bias, out);
  } else {
    hipMemsetAsync(d_out, 0, (size_t)NOUT * sizeof(float), stream);
    bilinear_main<1><<<NBLK, 512, 0, stream>>>(x, W, bias, P, out);
  }
}